// Round 12
// baseline (148.486 us; speedup 1.0000x reference)
//
#include <hip/hip_runtime.h>
#include <hip/hip_bf16.h>
#include <stdint.h>

typedef float f32x4 __attribute__((ext_vector_type(4)));
typedef short s16x8 __attribute__((ext_vector_type(8)));
typedef long long ll2 __attribute__((ext_vector_type(2)));
typedef unsigned short u16;
typedef uint8_t u8;

#define LOG2E 1.44269504088896340736f
#define FP8MAX 448.0f   // OCP e4m3fn max normal

#if __has_builtin(__builtin_amdgcn_exp2f)
#define EXP2F __builtin_amdgcn_exp2f
#else
#define EXP2F exp2f
#endif

__device__ __forceinline__ u16 f2bf(float f) {
    union { float f; uint32_t u; } v; v.f = f;
    uint32_t r = v.u + 0x7FFFu + ((v.u >> 16) & 1u);
    return (u16)(r >> 16);
}
__device__ __forceinline__ uint32_t cvt2bf(float lo, float hi) {
    __hip_bfloat162 h = __float22bfloat162_rn(float2{lo, hi});
    union { __hip_bfloat162 h; uint32_t u; } v; v.h = h; return v.u;
}
__device__ __forceinline__ float bflo2f(uint32_t u) {
    union { uint32_t u; float f; } v; v.u = u << 16; return v.f;
}
__device__ __forceinline__ float bfhi2f(uint32_t u) {
    union { uint32_t u; float f; } v; v.u = u & 0xffff0000u; return v.f;
}
__device__ __forceinline__ uint32_t cvt4fp8(float a, float b, float c, float d) {
    int w = __builtin_amdgcn_cvt_pk_fp8_f32(a, b, 0, false);
    w     = __builtin_amdgcn_cvt_pk_fp8_f32(c, d, w, true);
    return (uint32_t)w;
}
// lgkmcnt-only workgroup barrier (global prefetches keep flying across it)
__device__ __forceinline__ void lds_barrier() {
    asm volatile("s_waitcnt lgkmcnt(0)\n\ts_barrier" ::: "memory");
}

// ---------------------------------------------------------------------------
// Kernel 1: QKV projection (unchanged; ~12us).
// ---------------------------------------------------------------------------
__global__ __launch_bounds__(256) void qkv_kernel(
    const float* __restrict__ x,
    const float* __restrict__ Wq, const float* __restrict__ bq,
    const float* __restrict__ Wk, const float* __restrict__ bk,
    const float* __restrict__ Wv, const float* __restrict__ bv,
    u16* __restrict__ QT, u16* __restrict__ KT, u8* __restrict__ Vg)
{
    const int tid  = threadIdx.x;
    const int lane = tid & 63;
    const int wave = tid >> 6;
    const int blk  = blockIdx.x;
    const int b    = blk >> 8;
    const int sub  = blk & 255;
    const int jt   = sub >> 2;
    const int cg   = sub & 3;
    const int j    = (jt << 6) + lane;

    const float* xb = x + (size_t)b * 64 * 4096 + j;
    float xv[64];
#pragma unroll
    for (int c = 0; c < 64; ++c) xv[c] = xb[(size_t)c * 4096];

#pragma unroll
    for (int co = 0; co < 4; ++co) {
        const int row = __builtin_amdgcn_readfirstlane(cg * 16 + wave * 4 + co);
        const float* wrow = Wv + row * 64;
        float acc = bv[row];
#pragma unroll
        for (int cin = 0; cin < 64; ++cin) acc += wrow[cin] * xv[cin];
        acc = fminf(fmaxf(acc, -FP8MAX), FP8MAX);
        Vg[((size_t)(b * 64 + row)) * 4096 + j] =
            (u8)(__builtin_amdgcn_cvt_pk_fp8_f32(acc, acc, 0, false) & 0xff);
    }

    if (cg == 0) {
        if (wave == 0) {
            union { u16 u[8]; uint4 v; } q;
#pragma unroll
            for (int d = 0; d < 8; ++d) {
                const float* wrow = Wq + d * 64;
                float acc = bq[d];
#pragma unroll
                for (int cin = 0; cin < 64; ++cin) acc += wrow[cin] * xv[cin];
                q.u[d] = f2bf(acc * LOG2E);
            }
            *(uint4*)(QT + ((size_t)b * 4096 + j) * 8) = q.v;
        } else if (wave == 1) {
            union { u16 u[8]; uint4 v; } k;
#pragma unroll
            for (int d = 0; d < 8; ++d) {
                const float* wrow = Wk + d * 64;
                float acc = bk[d];
#pragma unroll
                for (int cin = 0; cin < 64; ++cin) acc += wrow[cin] * xv[cin];
                k.u[d] = f2bf(acc);
            }
            *(uint4*)(KT + ((size_t)b * 4096 + j) * 8) = k.v;
        }
    }
}

// ---------------------------------------------------------------------------
// Kernel 2: flash attention, fp8 V/P, split-K in-block, LDS-staged V.
// R11 additions targeting the DS-pipe + barrier-convoy residual:
//  (1) PERMUTED key layout in LDS: key k stored at byte
//      pos(k) = ((k>>3)&3)*16 + (k>=32 ? 8 : 0) + (k&7)
//      so a lane's two MFMA k-tiles are 16 contiguous bytes ->
//      one ds_read_b128 replaces two ds_read_b64 (P: 2->1, V: 8->4).
//  (2) 128-key iterations (2 x 64-key subtiles per barrier): barrier count
//      16->8, longer straightline region for cross-subtile overlap.
// P ping-pong parity == subtile parity s (u=2t+s). V double-buffer per iter.
// ---------------------------------------------------------------------------
#define P_STRIDE 80   // BYTES per P row (64 data + 16 pad; 16-aligned)
#define VROW 144      // BYTES per V row (128 data + 16 pad; 16-aligned)
#define OXW 65        // u32 elems per packed-Ox row

__global__ __launch_bounds__(1024, 4) void attn_kernel(
    const u16* __restrict__ QT, const u16* __restrict__ KT,
    const u8* __restrict__ Vg, const float* __restrict__ x,
    const float* __restrict__ gamma, float* __restrict__ out)
{
    __shared__ alignas(16) u8 p_lds[16][2][16 * P_STRIDE];  // 40960 B
    __shared__ alignas(16) u8 vbuf[4][2][64 * VROW];        // 73728 B
    __shared__ uint32_t OxP[12][8 * OXW];                   // 24960 B
    __shared__ float    Lx[12 * 16];                        //   768 B ~137KB

    const int tid  = threadIdx.x;
    const int lane = tid & 63;
    const int wave = tid >> 6;
    const int col  = lane & 15;
    const int quad = lane >> 4;
    const int qg   = wave & 3;          // query group
    const int sp   = wave >> 2;         // key split
    const int blk  = blockIdx.x;
    const int b    = blk >> 6;
    const int i0   = (blk & 63) << 6;
    const int iw   = i0 + qg * 16;      // this wave's first query

    const u16* KTb = KT + (size_t)b * 4096 * 8;
    const u8*  Vb  = Vg + (size_t)b * 64 * 4096;

    const s16x8 z8 = {0,0,0,0,0,0,0,0};
    const f32x4 zero = {0.f, 0.f, 0.f, 0.f};

    // Q fragment (B operand of S^T = K.Q^T): quad0 holds Q[iw+col][0..7]
    s16x8 aq = z8;
    if (quad == 0)
        aq = *(const s16x8*)(QT + ((size_t)b * 4096 + iw + col) * 8);

    f32x4 o[4];
#pragma unroll
    for (int nt = 0; nt < 4; ++nt) o[nt] = zero;
    float lsum = 0.f;

    u8* plA = &p_lds[wave][0][0];   // pl[s=0]
    u8* plB = &p_lds[wave][1][0];   // pl[s=1]

    // V staging role: row srow (channel), 16-B chunk schk (keys schk*16..+15
    // of a subtile). Permuted deposit offsets for that chunk:
    const int srow = (qg << 4) + (lane >> 2);
    const int schk = lane & 3;
    const int posA = (((2 * schk) & 3) << 4) + (((2 * schk) >> 2) << 3);
    const int posB = (((2 * schk + 1) & 3) << 4) + (((2 * schk + 1) >> 2) << 3);
    const u8* vsrc = Vb + (size_t)srow * 4096 + schk * 16;
    u8* vrow0 = &vbuf[sp][0][srow * VROW];
    u8* vrow1 = &vbuf[sp][1][srow * VROW];

    const int jbeg = sp << 10;

    // ---- prologue: K(iter0, both subtiles) + stage V(iter0) -> vbuf[0] ----
    s16x8 kb[2][4];
#pragma unroll
    for (int s = 0; s < 2; ++s)
#pragma unroll
        for (int nt = 0; nt < 4; ++nt) {
            s16x8 kn = z8;
            if (quad == 0)
                kn = *(const s16x8*)(KTb + (size_t)(jbeg + s * 64 + nt * 16 + col) * 8);
            kb[s][nt] = kn;
        }
    {
        uint4 v0 = *(const uint4*)(vsrc + jbeg);
        uint4 v1 = *(const uint4*)(vsrc + jbeg + 64);
        *(uint2*)(vrow0 + posA)      = make_uint2(v0.x, v0.y);
        *(uint2*)(vrow0 + posB)      = make_uint2(v0.z, v0.w);
        *(uint2*)(vrow0 + 64 + posA) = make_uint2(v1.x, v1.y);
        *(uint2*)(vrow0 + 64 + posB) = make_uint2(v1.z, v1.w);
    }
    lds_barrier();   // publish iter-0 V tile

    ll2 ap = {0, 0};

#pragma unroll 2
    for (int t = 0; t < 8; ++t) {
        const int j0 = jbeg + (t << 7);

        // 0) stage-load V(iter t+1): 2 x uint4 per lane
        uint4 vstg0, vstg1;
        if (t < 7) {
            vstg0 = *(const uint4*)(vsrc + j0 + 128);
            vstg1 = *(const uint4*)(vsrc + j0 + 192);
        }

#pragma unroll
        for (int s = 0; s < 2; ++s) {
            const int u = 2 * t + s;

            // 1) P(u-1) frags: one b128 from pl[s^1]
            if (u > 0)
                ap = *(const ll2*)((s ? plA : plB) + col * P_STRIDE + quad * 16);

            // 2) S^T(u): A = K (m=key), B = Q (n=query)
            f32x4 sv[4];
#pragma unroll
            for (int nt = 0; nt < 4; ++nt)
                sv[nt] = __builtin_amdgcn_mfma_f32_16x16x32_bf16(kb[s][nt], aq, zero, 0, 0, 0);

            // 3) K prefetch for iter t+1, subtile s
            if (t < 7) {
#pragma unroll
                for (int nt = 0; nt < 4; ++nt) {
                    s16x8 kn = z8;
                    if (quad == 0)
                        kn = *(const s16x8*)(KTb + (size_t)(j0 + 128 + s * 64 + nt * 16 + col) * 8);
                    kb[s][nt] = kn;
                }
            }

            // 4) P(u) = min(exp2,448); lsum; 4 fp8/u32 at PERMUTED offsets
            {
                u8* plw = s ? plB : plA;
#pragma unroll
                for (int nt = 0; nt < 4; ++nt) {
                    float p0 = fminf(EXP2F(sv[nt][0]), FP8MAX);
                    float p1 = fminf(EXP2F(sv[nt][1]), FP8MAX);
                    float p2 = fminf(EXP2F(sv[nt][2]), FP8MAX);
                    float p3 = fminf(EXP2F(sv[nt][3]), FP8MAX);
                    lsum += (p0 + p1) + (p2 + p3);
                    // key block b8 = nt*2 + (quad>>1); pos per permutation
                    const int pos = ((nt & 1) * 2 + (quad >> 1)) * 16
                                  + ((nt >> 1) * 8) + (quad & 1) * 4;
                    *(uint32_t*)(plw + col * P_STRIDE + pos) = cvt4fp8(p0, p1, p2, p3);
                }
            }
            asm volatile("" ::: "memory");   // no-reorder: P stores vs next reads

            // 5) PV(u-1): V frags = one b128 per nt from permuted tile
            if (u > 0) {
                const int tv = (u - 1) >> 1, svp = (u - 1) & 1;
                const u8* vt = &vbuf[sp][tv & 1][svp * 64];
#pragma unroll
                for (int nt = 0; nt < 4; ++nt) {
                    ll2 vv = *(const ll2*)(vt + (nt * 16 + col) * VROW + quad * 16);
                    o[nt] = __builtin_amdgcn_mfma_f32_16x16x32_fp8_fp8(ap.x, vv.x, o[nt], 0, 0, 0);
                    o[nt] = __builtin_amdgcn_mfma_f32_16x16x32_fp8_fp8(ap.y, vv.y, o[nt], 0, 0, 0);
                }
            }
        }

        // 6) rendezvous (lgkmcnt-only), then deposit V(t+1) into vbuf[(t+1)&1]
        lds_barrier();
        if (t < 7) {
            u8* vd = (t & 1) ? vrow0 : vrow1;
            *(uint2*)(vd + posA)      = make_uint2(vstg0.x, vstg0.y);
            *(uint2*)(vd + posB)      = make_uint2(vstg0.z, vstg0.w);
            *(uint2*)(vd + 64 + posA) = make_uint2(vstg1.x, vstg1.y);
            *(uint2*)(vd + 64 + posB) = make_uint2(vstg1.z, vstg1.w);
        }
    }

    // ---- epilogue: PV(15): P in pl[1], V subtile (t=7,s=1) in vbuf[1] ----
    {
        ap = *(const ll2*)(plB + col * P_STRIDE + quad * 16);
        const u8* vt = &vbuf[sp][1][64];
#pragma unroll
        for (int nt = 0; nt < 4; ++nt) {
            ll2 vv = *(const ll2*)(vt + (nt * 16 + col) * VROW + quad * 16);
            o[nt] = __builtin_amdgcn_mfma_f32_16x16x32_fp8_fp8(ap.x, vv.x, o[nt], 0, 0, 0);
            o[nt] = __builtin_amdgcn_mfma_f32_16x16x32_fp8_fp8(ap.y, vv.y, o[nt], 0, 0, 0);
        }
    }

    // ---- reduce lsum across quads: every lane -> l[query=col] ----
    lsum += __shfl_xor(lsum, 16, 64);
    lsum += __shfl_xor(lsum, 32, 64);

    // ---- combine the 4 key-splits in LDS ----
    if (sp > 0) {
        const int slice = (sp - 1) * 4 + qg;
        uint32_t* ox = &OxP[slice][0];
#pragma unroll
        for (int nt = 0; nt < 4; ++nt) {
#pragma unroll
            for (int rp = 0; rp < 2; ++rp)
                ox[(quad * 2 + rp) * OXW + nt * 16 + col] =
                    cvt2bf(o[nt][2 * rp], o[nt][2 * rp + 1]);
        }
        if (quad == 0) Lx[slice * 16 + col] = lsum;
    }
    __syncthreads();   // full barrier: OxP/Lx cross-wave publish (once)
    if (sp == 0) {
        float ltot = lsum;
#pragma unroll
        for (int s = 0; s < 3; ++s)
            ltot += Lx[(s * 4 + qg) * 16 + col];
        float linv[4];
#pragma unroll
        for (int r = 0; r < 4; ++r)
            linv[r] = 1.0f / __shfl(ltot, quad * 4 + r, 16);

#pragma unroll
        for (int s = 0; s < 3; ++s) {
            const uint32_t* ox = &OxP[s * 4 + qg][0];
#pragma unroll
            for (int nt = 0; nt < 4; ++nt) {
#pragma unroll
                for (int rp = 0; rp < 2; ++rp) {
                    uint32_t u = ox[(quad * 2 + rp) * OXW + nt * 16 + col];
                    o[nt][2 * rp]     += bflo2f(u);
                    o[nt][2 * rp + 1] += bfhi2f(u);
                }
            }
        }
        const float g = gamma[0];
#pragma unroll
        for (int nt = 0; nt < 4; ++nt) {
            const int c = nt * 16 + col;
#pragma unroll
            for (int r = 0; r < 4; ++r) {
                const int i = iw + quad * 4 + r;
                const size_t idx = ((size_t)(b * 64 + c)) * 4096 + i;
                out[idx] = g * (o[nt][r] * linv[r]) + x[idx];
            }
        }
    }
}

// ---------------------------------------------------------------------------
extern "C" void kernel_launch(void* const* d_in, const int* in_sizes, int n_in,
                              void* d_out, int out_size, void* d_ws, size_t ws_size,
                              hipStream_t stream)
{
    const float* x     = (const float*)d_in[0];
    const float* Wq    = (const float*)d_in[1];
    const float* bq    = (const float*)d_in[2];
    const float* Wk    = (const float*)d_in[3];
    const float* bk    = (const float*)d_in[4];
    const float* Wv    = (const float*)d_in[5];
    const float* bv    = (const float*)d_in[6];
    const float* gamma = (const float*)d_in[7];

    u16* QT = (u16*)d_ws;                 // [4][4096][8]  bf16
    u16* KT = QT + (size_t)4 * 4096 * 8;  // [4][4096][8]  bf16
    u8*  Vg = (u8*)(KT + (size_t)4 * 4096 * 8);  // [4][64][4096] fp8 e4m3

    qkv_kernel<<<1024, 256, 0, stream>>>(x, Wq, bq, Wk, bk, Wv, bv, QT, KT, Vg);
    attn_kernel<<<256, 1024, 0, stream>>>(QT, KT, Vg, x, gamma, (float*)d_out);
}

// Round 13
// 105.840 us; speedup vs baseline: 1.4029x; 1.4029x over previous
//
#include <hip/hip_runtime.h>
#include <hip/hip_bf16.h>
#include <stdint.h>

typedef float f32x4 __attribute__((ext_vector_type(4)));
typedef short s16x8 __attribute__((ext_vector_type(8)));
typedef unsigned short u16;
typedef uint8_t u8;

#define LOG2E 1.44269504088896340736f
#define FP8MAX 448.0f   // OCP e4m3fn max normal

#if __has_builtin(__builtin_amdgcn_exp2f)
#define EXP2F __builtin_amdgcn_exp2f
#else
#define EXP2F exp2f
#endif

__device__ __forceinline__ u16 f2bf(float f) {
    union { float f; uint32_t u; } v; v.f = f;
    uint32_t r = v.u + 0x7FFFu + ((v.u >> 16) & 1u);
    return (u16)(r >> 16);
}
__device__ __forceinline__ uint32_t cvt2bf(float lo, float hi) {
    __hip_bfloat162 h = __float22bfloat162_rn(float2{lo, hi});
    union { __hip_bfloat162 h; uint32_t u; } v; v.h = h; return v.u;
}
__device__ __forceinline__ float bflo2f(uint32_t u) {
    union { uint32_t u; float f; } v; v.u = u << 16; return v.f;
}
__device__ __forceinline__ float bfhi2f(uint32_t u) {
    union { uint32_t u; float f; } v; v.u = u & 0xffff0000u; return v.f;
}
__device__ __forceinline__ uint32_t cvt4fp8(float a, float b, float c, float d) {
    int w = __builtin_amdgcn_cvt_pk_fp8_f32(a, b, 0, false);
    w     = __builtin_amdgcn_cvt_pk_fp8_f32(c, d, w, true);
    return (uint32_t)w;
}
__device__ __forceinline__ void ds_write16(u8* d, uint4 v) {
    uint2 lo; lo.x = v.x; lo.y = v.y;
    uint2 hi; hi.x = v.z; hi.y = v.w;
    *(uint2*)(d)     = lo;
    *(uint2*)(d + 8) = hi;
}
// lgkmcnt-only workgroup barrier (global prefetches keep flying across it)
__device__ __forceinline__ void lds_barrier() {
    asm volatile("s_waitcnt lgkmcnt(0)\n\ts_barrier" ::: "memory");
}

// ---------------------------------------------------------------------------
// Kernel 1: QKV projection (unchanged; ~12us).
// ---------------------------------------------------------------------------
__global__ __launch_bounds__(256) void qkv_kernel(
    const float* __restrict__ x,
    const float* __restrict__ Wq, const float* __restrict__ bq,
    const float* __restrict__ Wk, const float* __restrict__ bk,
    const float* __restrict__ Wv, const float* __restrict__ bv,
    u16* __restrict__ QT, u16* __restrict__ KT, u8* __restrict__ Vg)
{
    const int tid  = threadIdx.x;
    const int lane = tid & 63;
    const int wave = tid >> 6;
    const int blk  = blockIdx.x;
    const int b    = blk >> 8;
    const int sub  = blk & 255;
    const int jt   = sub >> 2;
    const int cg   = sub & 3;
    const int j    = (jt << 6) + lane;

    const float* xb = x + (size_t)b * 64 * 4096 + j;
    float xv[64];
#pragma unroll
    for (int c = 0; c < 64; ++c) xv[c] = xb[(size_t)c * 4096];

#pragma unroll
    for (int co = 0; co < 4; ++co) {
        const int row = __builtin_amdgcn_readfirstlane(cg * 16 + wave * 4 + co);
        const float* wrow = Wv + row * 64;
        float acc = bv[row];
#pragma unroll
        for (int cin = 0; cin < 64; ++cin) acc += wrow[cin] * xv[cin];
        acc = fminf(fmaxf(acc, -FP8MAX), FP8MAX);
        Vg[((size_t)(b * 64 + row)) * 4096 + j] =
            (u8)(__builtin_amdgcn_cvt_pk_fp8_f32(acc, acc, 0, false) & 0xff);
    }

    if (cg == 0) {
        if (wave == 0) {
            union { u16 u[8]; uint4 v; } q;
#pragma unroll
            for (int d = 0; d < 8; ++d) {
                const float* wrow = Wq + d * 64;
                float acc = bq[d];
#pragma unroll
                for (int cin = 0; cin < 64; ++cin) acc += wrow[cin] * xv[cin];
                q.u[d] = f2bf(acc * LOG2E);
            }
            *(uint4*)(QT + ((size_t)b * 4096 + j) * 8) = q.v;
        } else if (wave == 1) {
            union { u16 u[8]; uint4 v; } k;
#pragma unroll
            for (int d = 0; d < 8; ++d) {
                const float* wrow = Wk + d * 64;
                float acc = bk[d];
#pragma unroll
                for (int cin = 0; cin < 64; ++cin) acc += wrow[cin] * xv[cin];
                k.u[d] = f2bf(acc);
            }
            *(uint4*)(KT + ((size_t)b * 4096 + j) * 8) = k.v;
        }
    }
}

// ---------------------------------------------------------------------------
// Kernel 2: flash attention, fp8 V/P, split-K in-block, LDS-staged V.
// EXACT R11 iteration body (no permute, no 128-key unroll — both spilled in
// R12). Decomposition change only: 512 blocks x 512 threads (8 waves =
// 2 qg x 4 sp; 32 queries/block), 68KB LDS -> TWO independent blocks per CU.
// Same 16 waves/CU, but two desynchronized barrier groups: when one parks
// at its barrier, the other keeps issuing (tests the lockstep-convoy theory).
// ---------------------------------------------------------------------------
#define P_STRIDE 72   // BYTES per P row (64 fp8 + 8 pad)
#define VROW 72       // BYTES per V-tile row (64 fp8 + 8 pad; 8 | 72)
#define OXW 65        // u32 elems per packed-Ox row

__global__ __launch_bounds__(512, 4) void attn_kernel(
    const u16* __restrict__ QT, const u16* __restrict__ KT,
    const u8* __restrict__ Vg, const float* __restrict__ x,
    const float* __restrict__ gamma, float* __restrict__ out)
{
    __shared__ alignas(16) u8 p_lds[8][2][16 * P_STRIDE];   // 18432 B
    __shared__ alignas(16) u8 vbuf[4][2][64 * VROW];        // 36864 B
    __shared__ uint32_t OxP[6][8 * OXW];                    // 12480 B
    __shared__ float    Lx[6 * 16];                         //   384 B ~68KB

    const int tid  = threadIdx.x;
    const int lane = tid & 63;
    const int wave = tid >> 6;       // 0..7
    const int col  = lane & 15;
    const int quad = lane >> 4;
    const int qg   = wave & 1;       // query group (2 per block)
    const int sp   = wave >> 1;      // key split (4)
    const int blk  = blockIdx.x;     // 512 blocks
    const int b    = blk >> 7;       // batch
    const int it   = blk & 127;      // i-tile of 32 queries
    const int iw   = (it << 5) + qg * 16;   // this wave's first query

    const u16* KTb = KT + (size_t)b * 4096 * 8;
    const u8*  Vb  = Vg + (size_t)b * 64 * 4096;

    const s16x8 z8 = {0,0,0,0,0,0,0,0};
    const f32x4 zero = {0.f, 0.f, 0.f, 0.f};

    // Q fragment (B operand of S^T = K.Q^T): quad0 holds Q[iw+col][0..7]
    s16x8 aq = z8;
    if (quad == 0)
        aq = *(const s16x8*)(QT + ((size_t)b * 4096 + iw + col) * 8);

    f32x4 o[4];
#pragma unroll
    for (int nt = 0; nt < 4; ++nt) o[nt] = zero;
    float lsum = 0.f;

    u8* plA = &p_lds[wave][0][0];
    u8* plB = &p_lds[wave][1][0];

    // V staging role: the sp-pair (2 waves x 64 lanes = 128 slots) covers
    // 64 rows x 2 half-rows (32B each). Lane loads 2 x uint4.
    const int sidx = qg * 64 + lane;        // 0..127 within the sp pair
    const int srow = sidx >> 1;             // channel row 0..63
    const int poff = (sidx & 1) * 32;       // 32B half of the 64B row
    const u8* vsrc = Vb + (size_t)srow * 4096 + poff;
    u8* vdst0 = &vbuf[sp][0][srow * VROW + poff];
    u8* vdst1 = &vbuf[sp][1][srow * VROW + poff];

    const int jbeg = sp << 10;

    // ---- prologue: K(0) frags + stage V(0) into vbuf[sp][0] ----
    s16x8 kb[4];
#pragma unroll
    for (int nt = 0; nt < 4; ++nt) {
        s16x8 kn = z8;
        if (quad == 0)
            kn = *(const s16x8*)(KTb + (size_t)(jbeg + nt * 16 + col) * 8);
        kb[nt] = kn;
    }
    ds_write16(vdst0,      *(const uint4*)(vsrc + jbeg));
    ds_write16(vdst0 + 16, *(const uint4*)(vsrc + jbeg + 16));
    lds_barrier();   // publish iter-0 V tile

    long long ap0 = 0, ap1 = 0;

#pragma unroll 2
    for (int t = 0; t < 16; ++t) {
        const int j0 = jbeg + (t << 6);
        u8* plw = (t & 1) ? plB : plA;   // P(t) target
        u8* plr = (t & 1) ? plA : plB;   // P(t-1) source

        // 0) stage-load V(t+1): 2 x uint4 per lane (consumed post-barrier)
        uint4 vstg0, vstg1;
        if (t < 15) {
            vstg0 = *(const uint4*)(vsrc + j0 + 64);
            vstg1 = *(const uint4*)(vsrc + j0 + 80);
        }

        // 1) P(t-1) frag reads
        if (t > 0) {
            ap0 = *(const long long*)(plr + col * P_STRIDE + quad * 8);
            ap1 = *(const long long*)(plr + col * P_STRIDE + 32 + quad * 8);
        }

        // 2) S^T(t): A = K (m=key), B = Q (n=query), bf16 K=32 (8 real dims)
        f32x4 s[4];
#pragma unroll
        for (int nt = 0; nt < 4; ++nt)
            s[nt] = __builtin_amdgcn_mfma_f32_16x16x32_bf16(kb[nt], aq, zero, 0, 0, 0);

        // 2b) prefetch K(t+1)
        if (t < 15) {
#pragma unroll
            for (int nt = 0; nt < 4; ++nt) {
                s16x8 kn = z8;
                if (quad == 0)
                    kn = *(const s16x8*)(KTb + (size_t)(j0 + 64 + nt * 16 + col) * 8);
                kb[nt] = kn;
            }
        }

        // 3) P(t) = min(exp2(S), 448); lsum; pack 4 fp8 -> one ds_write_b32
#pragma unroll
        for (int nt = 0; nt < 4; ++nt) {
            float p0 = fminf(EXP2F(s[nt][0]), FP8MAX);
            float p1 = fminf(EXP2F(s[nt][1]), FP8MAX);
            float p2 = fminf(EXP2F(s[nt][2]), FP8MAX);
            float p3 = fminf(EXP2F(s[nt][3]), FP8MAX);
            lsum += (p0 + p1) + (p2 + p3);
            *(uint32_t*)(plw + col * P_STRIDE + nt * 16 + quad * 4) =
                cvt4fp8(p0, p1, p2, p3);
        }
        // Ordering barrier: forbid hoisting next iteration's ap reads above
        // these stores (distinct TBAA types would otherwise permit it).
        asm volatile("" ::: "memory");

        // 4) V(t-1) frags from LDS tile + PV(t-1)
        if (t > 0) {
            const u8* vt = &vbuf[sp][(t - 1) & 1][0];
#pragma unroll
            for (int nt = 0; nt < 4; ++nt) {
                long long b0 = *(const long long*)(vt + (nt * 16 + col) * VROW + quad * 8);
                long long b1 = *(const long long*)(vt + (nt * 16 + col) * VROW + quad * 8 + 32);
                o[nt] = __builtin_amdgcn_mfma_f32_16x16x32_fp8_fp8(ap0, b0, o[nt], 0, 0, 0);
                o[nt] = __builtin_amdgcn_mfma_f32_16x16x32_fp8_fp8(ap1, b1, o[nt], 0, 0, 0);
            }
        }

        // 5) rendezvous (lgkmcnt-only; K/V prefetches keep flying)
        lds_barrier();

        // 6) deposit V(t+1) into vbuf[sp][(t+1)&1]
        if (t < 15) {
            u8* vd = (t & 1) ? vdst0 : vdst1;
            ds_write16(vd,      vstg0);
            ds_write16(vd + 16, vstg1);
        }
    }

    // ---- epilogue: PV(15): P in plB, V(15) in vbuf[sp][1] ----
    {
        ap0 = *(const long long*)(plB + col * P_STRIDE + quad * 8);
        ap1 = *(const long long*)(plB + col * P_STRIDE + 32 + quad * 8);
        const u8* vt = &vbuf[sp][1][0];
#pragma unroll
        for (int nt = 0; nt < 4; ++nt) {
            long long b0 = *(const long long*)(vt + (nt * 16 + col) * VROW + quad * 8);
            long long b1 = *(const long long*)(vt + (nt * 16 + col) * VROW + quad * 8 + 32);
            o[nt] = __builtin_amdgcn_mfma_f32_16x16x32_fp8_fp8(ap0, b0, o[nt], 0, 0, 0);
            o[nt] = __builtin_amdgcn_mfma_f32_16x16x32_fp8_fp8(ap1, b1, o[nt], 0, 0, 0);
        }
    }

    // ---- reduce lsum across quads: every lane -> l[query=col] ----
    lsum += __shfl_xor(lsum, 16, 64);
    lsum += __shfl_xor(lsum, 32, 64);

    // ---- combine the 4 key-splits in LDS ----
    if (sp > 0) {
        const int slice = (sp - 1) * 2 + qg;
        uint32_t* ox = &OxP[slice][0];
#pragma unroll
        for (int nt = 0; nt < 4; ++nt) {
#pragma unroll
            for (int rp = 0; rp < 2; ++rp)
                ox[(quad * 2 + rp) * OXW + nt * 16 + col] =
                    cvt2bf(o[nt][2 * rp], o[nt][2 * rp + 1]);
        }
        if (quad == 0) Lx[slice * 16 + col] = lsum;
    }
    __syncthreads();   // full barrier: OxP/Lx cross-wave publish (once)
    if (sp == 0) {
        float ltot = lsum;
#pragma unroll
        for (int s = 0; s < 3; ++s)
            ltot += Lx[(s * 2 + qg) * 16 + col];
        float linv[4];
#pragma unroll
        for (int r = 0; r < 4; ++r)
            linv[r] = 1.0f / __shfl(ltot, quad * 4 + r, 16);

#pragma unroll
        for (int s = 0; s < 3; ++s) {
            const uint32_t* ox = &OxP[s * 2 + qg][0];
#pragma unroll
            for (int nt = 0; nt < 4; ++nt) {
#pragma unroll
                for (int rp = 0; rp < 2; ++rp) {
                    uint32_t u = ox[(quad * 2 + rp) * OXW + nt * 16 + col];
                    o[nt][2 * rp]     += bflo2f(u);
                    o[nt][2 * rp + 1] += bfhi2f(u);
                }
            }
        }
        const float g = gamma[0];
#pragma unroll
        for (int nt = 0; nt < 4; ++nt) {
            const int c = nt * 16 + col;
#pragma unroll
            for (int r = 0; r < 4; ++r) {
                const int i = iw + quad * 4 + r;
                const size_t idx = ((size_t)(b * 64 + c)) * 4096 + i;
                out[idx] = g * (o[nt][r] * linv[r]) + x[idx];
            }
        }
    }
}

// ---------------------------------------------------------------------------
extern "C" void kernel_launch(void* const* d_in, const int* in_sizes, int n_in,
                              void* d_out, int out_size, void* d_ws, size_t ws_size,
                              hipStream_t stream)
{
    const float* x     = (const float*)d_in[0];
    const float* Wq    = (const float*)d_in[1];
    const float* bq    = (const float*)d_in[2];
    const float* Wk    = (const float*)d_in[3];
    const float* bk    = (const float*)d_in[4];
    const float* Wv    = (const float*)d_in[5];
    const float* bv    = (const float*)d_in[6];
    const float* gamma = (const float*)d_in[7];

    u16* QT = (u16*)d_ws;                 // [4][4096][8]  bf16
    u16* KT = QT + (size_t)4 * 4096 * 8;  // [4][4096][8]  bf16
    u8*  Vg = (u8*)(KT + (size_t)4 * 4096 * 8);  // [4][64][4096] fp8 e4m3

    qkv_kernel<<<1024, 256, 0, stream>>>(x, Wq, bq, Wk, bk, Wv, bv, QT, KT, Vg);
    attn_kernel<<<512, 512, 0, stream>>>(QT, KT, Vg, x, gamma, (float*)d_out);
}

// Round 14
// 102.468 us; speedup vs baseline: 1.4491x; 1.0329x over previous
//
#include <hip/hip_runtime.h>
#include <hip/hip_bf16.h>
#include <stdint.h>

typedef float f32x4 __attribute__((ext_vector_type(4)));
typedef short s16x8 __attribute__((ext_vector_type(8)));
typedef unsigned short u16;
typedef uint8_t u8;

#define LOG2E 1.44269504088896340736f
#define FP8MAX 448.0f   // OCP e4m3fn max normal

#if __has_builtin(__builtin_amdgcn_exp2f)
#define EXP2F __builtin_amdgcn_exp2f
#else
#define EXP2F exp2f
#endif

__device__ __forceinline__ u16 f2bf(float f) {
    union { float f; uint32_t u; } v; v.f = f;
    uint32_t r = v.u + 0x7FFFu + ((v.u >> 16) & 1u);
    return (u16)(r >> 16);
}
__device__ __forceinline__ uint32_t cvt2bf(float lo, float hi) {
    __hip_bfloat162 h = __float22bfloat162_rn(float2{lo, hi});
    union { __hip_bfloat162 h; uint32_t u; } v; v.h = h; return v.u;
}
__device__ __forceinline__ float bflo2f(uint32_t u) {
    union { uint32_t u; float f; } v; v.u = u << 16; return v.f;
}
__device__ __forceinline__ float bfhi2f(uint32_t u) {
    union { uint32_t u; float f; } v; v.u = u & 0xffff0000u; return v.f;
}
__device__ __forceinline__ uint32_t cvt4fp8(float a, float b, float c, float d) {
    int w = __builtin_amdgcn_cvt_pk_fp8_f32(a, b, 0, false);
    w     = __builtin_amdgcn_cvt_pk_fp8_f32(c, d, w, true);
    return (uint32_t)w;
}
__device__ __forceinline__ void ds_write16(u8* d, uint4 v) {
    uint2 lo; lo.x = v.x; lo.y = v.y;
    uint2 hi; hi.x = v.z; hi.y = v.w;
    *(uint2*)(d)     = lo;
    *(uint2*)(d + 8) = hi;
}
// lgkmcnt-only workgroup barrier (global prefetches keep flying across it)
__device__ __forceinline__ void lds_barrier() {
    asm volatile("s_waitcnt lgkmcnt(0)\n\ts_barrier" ::: "memory");
}

// ---------------------------------------------------------------------------
// Kernel 1: QKV projection (unchanged; ~12us).
// ---------------------------------------------------------------------------
__global__ __launch_bounds__(256) void qkv_kernel(
    const float* __restrict__ x,
    const float* __restrict__ Wq, const float* __restrict__ bq,
    const float* __restrict__ Wk, const float* __restrict__ bk,
    const float* __restrict__ Wv, const float* __restrict__ bv,
    u16* __restrict__ QT, u16* __restrict__ KT, u8* __restrict__ Vg)
{
    const int tid  = threadIdx.x;
    const int lane = tid & 63;
    const int wave = tid >> 6;
    const int blk  = blockIdx.x;
    const int b    = blk >> 8;
    const int sub  = blk & 255;
    const int jt   = sub >> 2;
    const int cg   = sub & 3;
    const int j    = (jt << 6) + lane;

    const float* xb = x + (size_t)b * 64 * 4096 + j;
    float xv[64];
#pragma unroll
    for (int c = 0; c < 64; ++c) xv[c] = xb[(size_t)c * 4096];

#pragma unroll
    for (int co = 0; co < 4; ++co) {
        const int row = __builtin_amdgcn_readfirstlane(cg * 16 + wave * 4 + co);
        const float* wrow = Wv + row * 64;
        float acc = bv[row];
#pragma unroll
        for (int cin = 0; cin < 64; ++cin) acc += wrow[cin] * xv[cin];
        acc = fminf(fmaxf(acc, -FP8MAX), FP8MAX);
        Vg[((size_t)(b * 64 + row)) * 4096 + j] =
            (u8)(__builtin_amdgcn_cvt_pk_fp8_f32(acc, acc, 0, false) & 0xff);
    }

    if (cg == 0) {
        if (wave == 0) {
            union { u16 u[8]; uint4 v; } q;
#pragma unroll
            for (int d = 0; d < 8; ++d) {
                const float* wrow = Wq + d * 64;
                float acc = bq[d];
#pragma unroll
                for (int cin = 0; cin < 64; ++cin) acc += wrow[cin] * xv[cin];
                q.u[d] = f2bf(acc * LOG2E);
            }
            *(uint4*)(QT + ((size_t)b * 4096 + j) * 8) = q.v;
        } else if (wave == 1) {
            union { u16 u[8]; uint4 v; } k;
#pragma unroll
            for (int d = 0; d < 8; ++d) {
                const float* wrow = Wk + d * 64;
                float acc = bk[d];
#pragma unroll
                for (int cin = 0; cin < 64; ++cin) acc += wrow[cin] * xv[cin];
                k.u[d] = f2bf(acc);
            }
            *(uint4*)(KT + ((size_t)b * 4096 + j) * 8) = k.v;
        }
    }
}

// ---------------------------------------------------------------------------
// Kernel 2: flash attention, fp8 V/P, split-K in-block, LDS-staged V,
// KEY-PERMUTED S-TILES -> NO P LDS ROUND-TRIP.
// S-tile nt covers key = j0 + (nt>>1)*32 + (col>>2)*8 + (nt&1)*4 + (col&3)
// (a pure addressing change in the per-lane K gather). Then lane (col,quad)'s
// C rows (quad*4+r) are keys quad*8 + (nt&1)*4 + r (+32 for nt>=2), so the
// packed exp results ARE the PV A-fragment: ap0=(w0,w1)=keys quad*8+0..7,
// ap1=(w2,w3)=keys 32+quad*8+0..7, natural order — V side unchanged.
// Removes per-iter: 4 P-writes + 2 P-reads + ping-pong + write->read latency.
//   iter t: stage-load V(t+1)->regs | S(t) mfma | K(t+1) prefetch |
//           exp/clamp/pack -> ap0,ap1 | lds_barrier (publishes V(t)) |
//           V(t) frags from vbuf[t&1] + PV(t) | deposit V(t+1)->vbuf[(t+1)&1]
// ---------------------------------------------------------------------------
#define VROW 72       // BYTES per V-tile row (64 fp8 + 8 pad; 8 | 72)
#define OXW 65        // u32 elems per packed-Ox row

__global__ __launch_bounds__(1024, 4) void attn_kernel(
    const u16* __restrict__ QT, const u16* __restrict__ KT,
    const u8* __restrict__ Vg, const float* __restrict__ x,
    const float* __restrict__ gamma, float* __restrict__ out)
{
    __shared__ alignas(16) u8 vbuf[4][2][64 * VROW];        // 36864 B
    __shared__ uint32_t OxP[12][8 * OXW];                   // 24960 B
    __shared__ float    Lx[12 * 16];                        //   768 B ~62.6KB

    const int tid  = threadIdx.x;
    const int lane = tid & 63;
    const int wave = tid >> 6;
    const int col  = lane & 15;
    const int quad = lane >> 4;
    const int qg   = wave & 3;          // query group
    const int sp   = wave >> 2;         // key split
    const int blk  = blockIdx.x;
    const int b    = blk >> 6;
    const int i0   = (blk & 63) << 6;
    const int iw   = i0 + qg * 16;      // this wave's first query

    const u16* KTb = KT + (size_t)b * 4096 * 8;
    const u8*  Vb  = Vg + (size_t)b * 64 * 4096;

    const s16x8 z8 = {0,0,0,0,0,0,0,0};
    const f32x4 zero = {0.f, 0.f, 0.f, 0.f};

    // permuted key column for the K gather (see header comment)
    const int pcol = ((col & 12) << 1) + (col & 3);

    // Q fragment (B operand of S^T = K.Q^T): quad0 holds Q[iw+col][0..7]
    s16x8 aq = z8;
    if (quad == 0)
        aq = *(const s16x8*)(QT + ((size_t)b * 4096 + iw + col) * 8);

    f32x4 o[4];
#pragma unroll
    for (int nt = 0; nt < 4; ++nt) o[nt] = zero;
    float lsum = 0.f;

    // V staging role: 4 qg-waves x 64 lanes cover 64 rows x 4 16B chunks
    const int srow = (qg << 4) + (lane >> 2);
    const int schk = lane & 3;
    const u8* vsrc = Vb + (size_t)srow * 4096 + schk * 16;
    u8* vdst0 = &vbuf[sp][0][srow * VROW + schk * 16];
    u8* vdst1 = &vbuf[sp][1][srow * VROW + schk * 16];

    const int jbeg = sp << 10;

    // ---- prologue: K(0) frags (permuted) + stage V(0) into vbuf[sp][0] ----
    s16x8 kb[4];
#pragma unroll
    for (int nt = 0; nt < 4; ++nt) {
        s16x8 kn = z8;
        if (quad == 0)
            kn = *(const s16x8*)(KTb +
                (size_t)(jbeg + ((nt >> 1) << 5) + ((nt & 1) << 2) + pcol) * 8);
        kb[nt] = kn;
    }
    ds_write16(vdst0, *(const uint4*)(vsrc + jbeg));

#pragma unroll 2
    for (int t = 0; t < 16; ++t) {
        const int j0 = jbeg + (t << 6);

        // a) stage-load V(t+1) (consumed post-barrier next iteration)
        uint4 vstg;
        if (t < 15) vstg = *(const uint4*)(vsrc + j0 + 64);

        // b) S^T(t): A = K (m=permuted key), B = Q (n=query)
        f32x4 s[4];
#pragma unroll
        for (int nt = 0; nt < 4; ++nt)
            s[nt] = __builtin_amdgcn_mfma_f32_16x16x32_bf16(kb[nt], aq, zero, 0, 0, 0);

        // c) prefetch K(t+1) (permuted)
        if (t < 15) {
#pragma unroll
            for (int nt = 0; nt < 4; ++nt) {
                s16x8 kn = z8;
                if (quad == 0)
                    kn = *(const s16x8*)(KTb +
                        (size_t)(j0 + 64 + ((nt >> 1) << 5) + ((nt & 1) << 2) + pcol) * 8);
                kb[nt] = kn;
            }
        }

        // d) P(t) = min(exp2(S),448); lsum; pack -> PV A-frags IN REGISTERS
        uint32_t w[4];
#pragma unroll
        for (int nt = 0; nt < 4; ++nt) {
            float p0 = fminf(EXP2F(s[nt][0]), FP8MAX);
            float p1 = fminf(EXP2F(s[nt][1]), FP8MAX);
            float p2 = fminf(EXP2F(s[nt][2]), FP8MAX);
            float p3 = fminf(EXP2F(s[nt][3]), FP8MAX);
            lsum += (p0 + p1) + (p2 + p3);
            w[nt] = cvt4fp8(p0, p1, p2, p3);
        }
        const long long ap0 = (long long)(((uint64_t)w[1] << 32) | w[0]);
        const long long ap1 = (long long)(((uint64_t)w[3] << 32) | w[2]);

        // e) publish V(t) (deposited by all waves last iteration)
        lds_barrier();

        // f) V(t) frags from vbuf[sp][t&1] + PV(t)
        {
            const u8* vt = &vbuf[sp][t & 1][0];
#pragma unroll
            for (int nt = 0; nt < 4; ++nt) {
                long long b0 = *(const long long*)(vt + (nt * 16 + col) * VROW + quad * 8);
                long long b1 = *(const long long*)(vt + (nt * 16 + col) * VROW + quad * 8 + 32);
                o[nt] = __builtin_amdgcn_mfma_f32_16x16x32_fp8_fp8(ap0, b0, o[nt], 0, 0, 0);
                o[nt] = __builtin_amdgcn_mfma_f32_16x16x32_fp8_fp8(ap1, b1, o[nt], 0, 0, 0);
            }
        }

        // g) deposit V(t+1) into vbuf[sp][(t+1)&1] (old occupant V(t-1) was
        //    read by all waves before barrier e; next barrier publishes this)
        if (t < 15) ds_write16((t & 1) ? vdst0 : vdst1, vstg);
    }

    // ---- reduce lsum across quads: every lane -> l[query=col] ----
    lsum += __shfl_xor(lsum, 16, 64);
    lsum += __shfl_xor(lsum, 32, 64);

    // ---- combine the 4 key-splits in LDS ----
    if (sp > 0) {
        const int slice = (sp - 1) * 4 + qg;
        uint32_t* ox = &OxP[slice][0];
#pragma unroll
        for (int nt = 0; nt < 4; ++nt) {
#pragma unroll
            for (int rp = 0; rp < 2; ++rp)
                ox[(quad * 2 + rp) * OXW + nt * 16 + col] =
                    cvt2bf(o[nt][2 * rp], o[nt][2 * rp + 1]);
        }
        if (quad == 0) Lx[slice * 16 + col] = lsum;
    }
    __syncthreads();   // full barrier: OxP/Lx cross-wave publish (once)
    if (sp == 0) {
        float ltot = lsum;
#pragma unroll
        for (int s = 0; s < 3; ++s)
            ltot += Lx[(s * 4 + qg) * 16 + col];
        float linv[4];
#pragma unroll
        for (int r = 0; r < 4; ++r)
            linv[r] = 1.0f / __shfl(ltot, quad * 4 + r, 16);

#pragma unroll
        for (int s = 0; s < 3; ++s) {
            const uint32_t* ox = &OxP[s * 4 + qg][0];
#pragma unroll
            for (int nt = 0; nt < 4; ++nt) {
#pragma unroll
                for (int rp = 0; rp < 2; ++rp) {
                    uint32_t u = ox[(quad * 2 + rp) * OXW + nt * 16 + col];
                    o[nt][2 * rp]     += bflo2f(u);
                    o[nt][2 * rp + 1] += bfhi2f(u);
                }
            }
        }
        const float g = gamma[0];
#pragma unroll
        for (int nt = 0; nt < 4; ++nt) {
            const int c = nt * 16 + col;
#pragma unroll
            for (int r = 0; r < 4; ++r) {
                const int i = iw + quad * 4 + r;
                const size_t idx = ((size_t)(b * 64 + c)) * 4096 + i;
                out[idx] = g * (o[nt][r] * linv[r]) + x[idx];
            }
        }
    }
}

// ---------------------------------------------------------------------------
extern "C" void kernel_launch(void* const* d_in, const int* in_sizes, int n_in,
                              void* d_out, int out_size, void* d_ws, size_t ws_size,
                              hipStream_t stream)
{
    const float* x     = (const float*)d_in[0];
    const float* Wq    = (const float*)d_in[1];
    const float* bq    = (const float*)d_in[2];
    const float* Wk    = (const float*)d_in[3];
    const float* bk    = (const float*)d_in[4];
    const float* Wv    = (const float*)d_in[5];
    const float* bv    = (const float*)d_in[6];
    const float* gamma = (const float*)d_in[7];

    u16* QT = (u16*)d_ws;                 // [4][4096][8]  bf16
    u16* KT = QT + (size_t)4 * 4096 * 8;  // [4][4096][8]  bf16
    u8*  Vg = (u8*)(KT + (size_t)4 * 4096 * 8);  // [4][64][4096] fp8 e4m3

    qkv_kernel<<<1024, 256, 0, stream>>>(x, Wq, bq, Wk, bk, Wv, bv, QT, KT, Vg);
    attn_kernel<<<256, 1024, 0, stream>>>(QT, KT, Vg, x, gamma, (float*)d_out);
}

// Round 15
// 97.543 us; speedup vs baseline: 1.5223x; 1.0505x over previous
//
#include <hip/hip_runtime.h>
#include <hip/hip_bf16.h>
#include <stdint.h>

typedef float f32x4 __attribute__((ext_vector_type(4)));
typedef short s16x8 __attribute__((ext_vector_type(8)));
typedef unsigned short u16;
typedef uint8_t u8;

#define LOG2E 1.44269504088896340736f
#define FP8MAX 448.0f   // OCP e4m3fn max normal

#if __has_builtin(__builtin_amdgcn_exp2f)
#define EXP2F __builtin_amdgcn_exp2f
#else
#define EXP2F exp2f
#endif

__device__ __forceinline__ u16 f2bf(float f) {
    union { float f; uint32_t u; } v; v.f = f;
    uint32_t r = v.u + 0x7FFFu + ((v.u >> 16) & 1u);
    return (u16)(r >> 16);
}
__device__ __forceinline__ uint32_t cvt2bf(float lo, float hi) {
    __hip_bfloat162 h = __float22bfloat162_rn(float2{lo, hi});
    union { __hip_bfloat162 h; uint32_t u; } v; v.h = h; return v.u;
}
__device__ __forceinline__ float bflo2f(uint32_t u) {
    union { uint32_t u; float f; } v; v.u = u << 16; return v.f;
}
__device__ __forceinline__ float bfhi2f(uint32_t u) {
    union { uint32_t u; float f; } v; v.u = u & 0xffff0000u; return v.f;
}
__device__ __forceinline__ uint32_t cvt4fp8(float a, float b, float c, float d) {
    int w = __builtin_amdgcn_cvt_pk_fp8_f32(a, b, 0, false);
    w     = __builtin_amdgcn_cvt_pk_fp8_f32(c, d, w, true);
    return (uint32_t)w;
}
__device__ __forceinline__ void ds_write16(u8* d, uint4 v) {
    uint2 lo; lo.x = v.x; lo.y = v.y;
    uint2 hi; hi.x = v.z; hi.y = v.w;
    *(uint2*)(d)     = lo;
    *(uint2*)(d + 8) = hi;
}
// lgkmcnt-only workgroup barrier (global prefetches keep flying across it)
__device__ __forceinline__ void lds_barrier() {
    asm volatile("s_waitcnt lgkmcnt(0)\n\ts_barrier" ::: "memory");
}

// ---------------------------------------------------------------------------
// Kernel 1: QKV projection — LOAD-BALANCED over all 80 output rows.
// R14 post-mortem: old structure gave cg0's waves 0/1 3x the work (4 V rows
// + 8 Q/K rows); 256 of 1024 blocks carried a 3x critical wave -> makespan
// ~12us vs ~4us balanced floor. Now: 5 row-groups of 16 (4 V-groups + 1
// QK-group); EVERY wave computes exactly 4 rows (4x64 FMA). Grid
// 4 x 64 x 5 = 1280 blocks x 256 threads (~20 waves/CU).
// ---------------------------------------------------------------------------
__global__ __launch_bounds__(256) void qkv_kernel(
    const float* __restrict__ x,
    const float* __restrict__ Wq, const float* __restrict__ bq,
    const float* __restrict__ Wk, const float* __restrict__ bk,
    const float* __restrict__ Wv, const float* __restrict__ bv,
    u16* __restrict__ QT, u16* __restrict__ KT, u8* __restrict__ Vg)
{
    const int tid  = threadIdx.x;
    const int lane = tid & 63;
    const int wave = tid >> 6;
    const int blk  = blockIdx.x;          // 1280 blocks
    const int b    = blk / 320;           // batch
    const int sub  = blk - b * 320;
    const int jt   = sub / 5;             // 64 j-tiles
    const int cg   = sub - jt * 5;        // 5 row groups of 16
    const int j    = (jt << 6) + lane;

    const float* xb = x + (size_t)b * 64 * 4096 + j;
    float xv[64];
#pragma unroll
    for (int c = 0; c < 64; ++c) xv[c] = xb[(size_t)c * 4096];

    if (cg < 4) {
        // 4 V rows per thread; row index in SGPR -> weights via s_load
#pragma unroll
        for (int co = 0; co < 4; ++co) {
            const int row = __builtin_amdgcn_readfirstlane(cg * 16 + wave * 4 + co);
            const float* wrow = Wv + row * 64;
            float acc = bv[row];
#pragma unroll
            for (int cin = 0; cin < 64; ++cin) acc += wrow[cin] * xv[cin];
            acc = fminf(fmaxf(acc, -FP8MAX), FP8MAX);
            Vg[((size_t)(b * 64 + row)) * 4096 + j] =
                (u8)(__builtin_amdgcn_cvt_pk_fp8_f32(acc, acc, 0, false) & 0xff);
        }
    } else {
        // QK group: waves 0,1 -> Q rows 0-7; waves 2,3 -> K rows 0-7.
        // Wave-uniform selection; 4 rows per wave (uniform with V groups).
        const bool isQ = (wave < 2);
        const float* Wqk = isQ ? Wq : Wk;
        const float* bqk = isQ ? bq : bk;
        const float scl  = isQ ? LOG2E : 1.0f;
        u16* dst = isQ ? QT : KT;
        const int w2 = wave & 1;
#pragma unroll
        for (int co = 0; co < 4; ++co) {
            const int d = __builtin_amdgcn_readfirstlane(w2 * 4 + co);
            const float* wrow = Wqk + d * 64;
            float acc = bqk[d];
#pragma unroll
            for (int cin = 0; cin < 64; ++cin) acc += wrow[cin] * xv[cin];
            dst[((size_t)b * 4096 + j) * 8 + d] = f2bf(acc * scl);
        }
    }
}

// ---------------------------------------------------------------------------
// Kernel 2: flash attention — BYTE-IDENTICAL to R14 (best: attn ~24us).
// fp8 V/P, split-K in-block, LDS-staged V, key-permuted S-tiles (P never
// touches LDS: packed exp results ARE the PV A-fragment).
// ---------------------------------------------------------------------------
#define VROW 72       // BYTES per V-tile row (64 fp8 + 8 pad; 8 | 72)
#define OXW 65        // u32 elems per packed-Ox row

__global__ __launch_bounds__(1024, 4) void attn_kernel(
    const u16* __restrict__ QT, const u16* __restrict__ KT,
    const u8* __restrict__ Vg, const float* __restrict__ x,
    const float* __restrict__ gamma, float* __restrict__ out)
{
    __shared__ alignas(16) u8 vbuf[4][2][64 * VROW];        // 36864 B
    __shared__ uint32_t OxP[12][8 * OXW];                   // 24960 B
    __shared__ float    Lx[12 * 16];                        //   768 B ~62.6KB

    const int tid  = threadIdx.x;
    const int lane = tid & 63;
    const int wave = tid >> 6;
    const int col  = lane & 15;
    const int quad = lane >> 4;
    const int qg   = wave & 3;          // query group
    const int sp   = wave >> 2;         // key split
    const int blk  = blockIdx.x;
    const int b    = blk >> 6;
    const int i0   = (blk & 63) << 6;
    const int iw   = i0 + qg * 16;      // this wave's first query

    const u16* KTb = KT + (size_t)b * 4096 * 8;
    const u8*  Vb  = Vg + (size_t)b * 64 * 4096;

    const s16x8 z8 = {0,0,0,0,0,0,0,0};
    const f32x4 zero = {0.f, 0.f, 0.f, 0.f};

    // permuted key column for the K gather
    const int pcol = ((col & 12) << 1) + (col & 3);

    // Q fragment (B operand of S^T = K.Q^T): quad0 holds Q[iw+col][0..7]
    s16x8 aq = z8;
    if (quad == 0)
        aq = *(const s16x8*)(QT + ((size_t)b * 4096 + iw + col) * 8);

    f32x4 o[4];
#pragma unroll
    for (int nt = 0; nt < 4; ++nt) o[nt] = zero;
    float lsum = 0.f;

    // V staging role: 4 qg-waves x 64 lanes cover 64 rows x 4 16B chunks
    const int srow = (qg << 4) + (lane >> 2);
    const int schk = lane & 3;
    const u8* vsrc = Vb + (size_t)srow * 4096 + schk * 16;
    u8* vdst0 = &vbuf[sp][0][srow * VROW + schk * 16];
    u8* vdst1 = &vbuf[sp][1][srow * VROW + schk * 16];

    const int jbeg = sp << 10;

    // ---- prologue: K(0) frags (permuted) + stage V(0) into vbuf[sp][0] ----
    s16x8 kb[4];
#pragma unroll
    for (int nt = 0; nt < 4; ++nt) {
        s16x8 kn = z8;
        if (quad == 0)
            kn = *(const s16x8*)(KTb +
                (size_t)(jbeg + ((nt >> 1) << 5) + ((nt & 1) << 2) + pcol) * 8);
        kb[nt] = kn;
    }
    ds_write16(vdst0, *(const uint4*)(vsrc + jbeg));

#pragma unroll 2
    for (int t = 0; t < 16; ++t) {
        const int j0 = jbeg + (t << 6);

        // a) stage-load V(t+1) (consumed post-barrier next iteration)
        uint4 vstg;
        if (t < 15) vstg = *(const uint4*)(vsrc + j0 + 64);

        // b) S^T(t): A = K (m=permuted key), B = Q (n=query)
        f32x4 s[4];
#pragma unroll
        for (int nt = 0; nt < 4; ++nt)
            s[nt] = __builtin_amdgcn_mfma_f32_16x16x32_bf16(kb[nt], aq, zero, 0, 0, 0);

        // c) prefetch K(t+1) (permuted)
        if (t < 15) {
#pragma unroll
            for (int nt = 0; nt < 4; ++nt) {
                s16x8 kn = z8;
                if (quad == 0)
                    kn = *(const s16x8*)(KTb +
                        (size_t)(j0 + 64 + ((nt >> 1) << 5) + ((nt & 1) << 2) + pcol) * 8);
                kb[nt] = kn;
            }
        }

        // d) P(t) = min(exp2(S),448); lsum; pack -> PV A-frags IN REGISTERS
        uint32_t w[4];
#pragma unroll
        for (int nt = 0; nt < 4; ++nt) {
            float p0 = fminf(EXP2F(s[nt][0]), FP8MAX);
            float p1 = fminf(EXP2F(s[nt][1]), FP8MAX);
            float p2 = fminf(EXP2F(s[nt][2]), FP8MAX);
            float p3 = fminf(EXP2F(s[nt][3]), FP8MAX);
            lsum += (p0 + p1) + (p2 + p3);
            w[nt] = cvt4fp8(p0, p1, p2, p3);
        }
        const long long ap0 = (long long)(((uint64_t)w[1] << 32) | w[0]);
        const long long ap1 = (long long)(((uint64_t)w[3] << 32) | w[2]);

        // e) publish V(t) (deposited by all waves last iteration)
        lds_barrier();

        // f) V(t) frags from vbuf[sp][t&1] + PV(t)
        {
            const u8* vt = &vbuf[sp][t & 1][0];
#pragma unroll
            for (int nt = 0; nt < 4; ++nt) {
                long long b0 = *(const long long*)(vt + (nt * 16 + col) * VROW + quad * 8);
                long long b1 = *(const long long*)(vt + (nt * 16 + col) * VROW + quad * 8 + 32);
                o[nt] = __builtin_amdgcn_mfma_f32_16x16x32_fp8_fp8(ap0, b0, o[nt], 0, 0, 0);
                o[nt] = __builtin_amdgcn_mfma_f32_16x16x32_fp8_fp8(ap1, b1, o[nt], 0, 0, 0);
            }
        }

        // g) deposit V(t+1) into vbuf[sp][(t+1)&1]
        if (t < 15) ds_write16((t & 1) ? vdst0 : vdst1, vstg);
    }

    // ---- reduce lsum across quads: every lane -> l[query=col] ----
    lsum += __shfl_xor(lsum, 16, 64);
    lsum += __shfl_xor(lsum, 32, 64);

    // ---- combine the 4 key-splits in LDS ----
    if (sp > 0) {
        const int slice = (sp - 1) * 4 + qg;
        uint32_t* ox = &OxP[slice][0];
#pragma unroll
        for (int nt = 0; nt < 4; ++nt) {
#pragma unroll
            for (int rp = 0; rp < 2; ++rp)
                ox[(quad * 2 + rp) * OXW + nt * 16 + col] =
                    cvt2bf(o[nt][2 * rp], o[nt][2 * rp + 1]);
        }
        if (quad == 0) Lx[slice * 16 + col] = lsum;
    }
    __syncthreads();   // full barrier: OxP/Lx cross-wave publish (once)
    if (sp == 0) {
        float ltot = lsum;
#pragma unroll
        for (int s = 0; s < 3; ++s)
            ltot += Lx[(s * 4 + qg) * 16 + col];
        float linv[4];
#pragma unroll
        for (int r = 0; r < 4; ++r)
            linv[r] = 1.0f / __shfl(ltot, quad * 4 + r, 16);

#pragma unroll
        for (int s = 0; s < 3; ++s) {
            const uint32_t* ox = &OxP[s * 4 + qg][0];
#pragma unroll
            for (int nt = 0; nt < 4; ++nt) {
#pragma unroll
                for (int rp = 0; rp < 2; ++rp) {
                    uint32_t u = ox[(quad * 2 + rp) * OXW + nt * 16 + col];
                    o[nt][2 * rp]     += bflo2f(u);
                    o[nt][2 * rp + 1] += bfhi2f(u);
                }
            }
        }
        const float g = gamma[0];
#pragma unroll
        for (int nt = 0; nt < 4; ++nt) {
            const int c = nt * 16 + col;
#pragma unroll
            for (int r = 0; r < 4; ++r) {
                const int i = iw + quad * 4 + r;
                const size_t idx = ((size_t)(b * 64 + c)) * 4096 + i;
                out[idx] = g * (o[nt][r] * linv[r]) + x[idx];
            }
        }
    }
}

// ---------------------------------------------------------------------------
extern "C" void kernel_launch(void* const* d_in, const int* in_sizes, int n_in,
                              void* d_out, int out_size, void* d_ws, size_t ws_size,
                              hipStream_t stream)
{
    const float* x     = (const float*)d_in[0];
    const float* Wq    = (const float*)d_in[1];
    const float* bq    = (const float*)d_in[2];
    const float* Wk    = (const float*)d_in[3];
    const float* bk    = (const float*)d_in[4];
    const float* Wv    = (const float*)d_in[5];
    const float* bv    = (const float*)d_in[6];
    const float* gamma = (const float*)d_in[7];

    u16* QT = (u16*)d_ws;                 // [4][4096][8]  bf16
    u16* KT = QT + (size_t)4 * 4096 * 8;  // [4][4096][8]  bf16
    u8*  Vg = (u8*)(KT + (size_t)4 * 4096 * 8);  // [4][64][4096] fp8 e4m3

    qkv_kernel<<<1280, 256, 0, stream>>>(x, Wq, bq, Wk, bk, Wv, bv, QT, KT, Vg);
    attn_kernel<<<256, 1024, 0, stream>>>(QT, KT, Vg, x, gamma, (float*)d_out);
}